// Round 6
// baseline (83.986 us; speedup 1.0000x reference)
//
#include <hip/hip_runtime.h>
#include <hip/hip_bf16.h>
#include <stdint.h>

// ---------- helpers ----------
typedef __attribute__((ext_vector_type(8))) __bf16 bf16x8;
typedef __attribute__((ext_vector_type(8))) unsigned short u16x8;
typedef __attribute__((ext_vector_type(4))) float f32x4;

__device__ inline float bf2f(unsigned short u) {
  union { unsigned u; float f; } z; z.u = ((unsigned)u) << 16; return z.f;
}
__device__ inline unsigned short f2bf(float f) {
  union { float f; unsigned u; } z; z.f = f;
  unsigned r = z.u + 0x7fffu + ((z.u >> 16) & 1u);
  return (unsigned short)(r >> 16);
}
__device__ inline void gload_lds16(const void* g, void* l) {
  __builtin_amdgcn_global_load_lds((const __attribute__((address_space(1))) void*)g,
                                   (__attribute__((address_space(3))) void*)l, 16, 0, 0);
}

// ---------- weight convert: f32->bf16 weights + rpe pack (513 blocks) ----------
__global__ __launch_bounds__(256) void wcvt(
    const float* __restrict__ Wq, const float* __restrict__ Wk, const float* __restrict__ Wv,
    const float* __restrict__ Wo, const float* __restrict__ We, const float* __restrict__ Ws,
    const float* __restrict__ Wrpe, const float* __restrict__ brpe,
    unsigned short* __restrict__ wqb, unsigned short* __restrict__ wkvb,
    unsigned short* __restrict__ wob, unsigned short* __restrict__ web,
    unsigned short* __restrict__ wsb, float4* __restrict__ rpe4) {
  const int b = blockIdx.x, t = threadIdx.x;
  const float* src; unsigned short* dst; long off;
  if (b < 64)       { src = Wq; dst = wqb;           off = (long)b * 1024; }
  else if (b < 128) { src = Wk; dst = wkvb;          off = (long)(b - 64) * 1024; }
  else if (b < 192) { src = Wv; dst = wkvb + 65536;  off = (long)(b - 128) * 1024; }
  else if (b < 256) { src = Wo; dst = wob;           off = (long)(b - 192) * 1024; }
  else if (b < 384) { src = We; dst = web;           off = (long)(b - 256) * 1024; }
  else if (b < 512) { src = Ws; dst = wsb;           off = (long)(b - 384) * 1024; }
  else {
    if (t < 128) {
      float4 r;
      r.x = Wrpe[3 * t]; r.y = Wrpe[3 * t + 1]; r.z = Wrpe[3 * t + 2]; r.w = brpe[t];
      rpe4[t] = r;
    }
    return;
  }
  const float4 v = *(const float4*)(src + off + t * 4);
  ushort4 o;
  o.x = f2bf(v.x); o.y = f2bf(v.y); o.z = f2bf(v.z); o.w = f2bf(v.w);
  *(ushort4*)(dst + off + t * 4) = o;
}

// ---------- fused q/k/v projection: f32 A (reg-staged cvt), bf16 W (gload_lds) ----------
// grid (128, 6): by 0-1 -> q (A=x), 2-3 -> k, 4-5 -> v (A=mem). BM=64, BN=128, K=256.
// kv output layout: kvp[m][512] = [K cols 0-127 | V cols 0-127 | K cols 128-255 | V cols 128-255]
__global__ __launch_bounds__(256, 2) void gemm_proj(
    const float* __restrict__ x, const float* __restrict__ mem,
    const unsigned short* __restrict__ wqb, const unsigned short* __restrict__ wkvb,
    const float* __restrict__ bq, const float* __restrict__ bk, const float* __restrict__ bv,
    unsigned short* __restrict__ qbuf, unsigned short* __restrict__ kvp) {
  __shared__ __attribute__((aligned(16))) char lds[4096 + 8192];  // A 4KB | B 8KB (bf16)
  const int tid = threadIdx.x, lane = tid & 63;
  const int wm = tid >> 7, wo = (tid >> 6) & 1;
  const long bm = blockIdx.x;
  const int by = blockIdx.y;

  const float* Ab; const unsigned short* Wb; const float* biasp;
  unsigned short* outp; int obase, ostride;
  if (by < 2) {
    Ab = x; Wb = wqb + (long)by * 128 * 256; biasp = bq + by * 128;
    outp = qbuf; obase = by * 128; ostride = 256;
  } else if (by < 4) {
    Ab = mem; Wb = wkvb + (long)(by - 2) * 128 * 256; biasp = bk + (by - 2) * 128;
    outp = kvp; obase = (by == 2) ? 0 : 256; ostride = 512;
  } else {
    Ab = mem; Wb = wkvb + (long)(by - 2) * 128 * 256; biasp = bv + (by - 4) * 128;
    outp = kvp; obase = (by == 4) ? 128 : 384; ostride = 512;
  }

  f32x4 acc[2][4] = {};
  for (int kt = 0; kt < 8; ++kt) {
    // A: 64 rows x 32 f32 -> bf16 LDS (64B/row)
#pragma unroll
    for (int c = 0; c < 2; ++c) {
      const int fb = c * 4096 + tid * 16;
      const int row = fb >> 7, colb = fb & 127;
      const float4 a4 = *(const float4*)((const char*)Ab + (bm * 64 + row) * 1024 + kt * 128 + colb);
      ushort4 o; o.x = f2bf(a4.x); o.y = f2bf(a4.y); o.z = f2bf(a4.z); o.w = f2bf(a4.w);
      *(ushort4*)(lds + row * 64 + (colb >> 1)) = o;
    }
    // W: 128 rows x 64B (bf16), async
#pragma unroll
    for (int c = 0; c < 2; ++c) {
      const int fb = c * 4096 + tid * 16;
      gload_lds16((const char*)Wb + (long)(fb >> 6) * 512 + kt * 64 + (fb & 63), lds + 4096 + fb);
    }
    __syncthreads();
    bf16x8 af[2], bfr[4];
    const int kb = (lane >> 4) * 16;
#pragma unroll
    for (int i = 0; i < 2; ++i)
      af[i] = *(const bf16x8*)(lds + (wm * 32 + i * 16 + (lane & 15)) * 64 + kb);
#pragma unroll
    for (int j = 0; j < 4; ++j)
      bfr[j] = *(const bf16x8*)(lds + 4096 + (wo * 64 + j * 16 + (lane & 15)) * 64 + kb);
#pragma unroll
    for (int i = 0; i < 2; ++i)
#pragma unroll
      for (int j = 0; j < 4; ++j)
        acc[i][j] = __builtin_amdgcn_mfma_f32_16x16x32_bf16(af[i], bfr[j], acc[i][j], 0, 0, 0);
    __syncthreads();
  }

#pragma unroll
  for (int i = 0; i < 2; ++i) {
#pragma unroll
    for (int j = 0; j < 4; ++j) {
      const int lc = wo * 64 + j * 16 + (lane & 15);
      const float bvv = biasp[lc];
#pragma unroll
      for (int r = 0; r < 4; ++r) {
        const long rowg = bm * 64 + wm * 32 + i * 16 + (lane >> 4) * 4 + r;
        outp[rowg * ostride + obase + lc] = f2bf(acc[i][j][r] + bvv);
      }
    }
  }
}

// ---------- bf16 GEMM + relu + bf16 out (FFN1). BM=64, BN=128 ----------
__global__ __launch_bounds__(256, 2) void gemm_relu(
    const unsigned short* __restrict__ A,   // M x 256
    const unsigned short* __restrict__ W,   // 512 x 256
    const float* __restrict__ bias,         // 512
    unsigned short* __restrict__ outb) {    // M x 512
  __shared__ __attribute__((aligned(16))) char lds[(64 + 128) * 64];
  const int tid = threadIdx.x, lane = tid & 63;
  const int wm = tid >> 7, wo = (tid >> 6) & 1;
  const long bm = blockIdx.x, bo = blockIdx.y;

  f32x4 acc[2][4] = {};
  const char* Ab = (const char*)(A + bm * 64 * 256);
  const char* Wb = (const char*)(W + bo * 128 * 256);
  for (int kt = 0; kt < 8; ++kt) {
    {
      const int fb = tid * 16;
      gload_lds16(Ab + (long)(fb >> 6) * 512 + kt * 64 + (fb & 63), lds + fb);
    }
#pragma unroll
    for (int c = 0; c < 2; ++c) {
      const int fb = c * 4096 + tid * 16;
      gload_lds16(Wb + (long)(fb >> 6) * 512 + kt * 64 + (fb & 63), lds + 4096 + fb);
    }
    __syncthreads();
    bf16x8 af[2], bfr[4];
    const int kb = (lane >> 4) * 16;
#pragma unroll
    for (int i = 0; i < 2; ++i)
      af[i] = *(const bf16x8*)(lds + (wm * 32 + i * 16 + (lane & 15)) * 64 + kb);
#pragma unroll
    for (int j = 0; j < 4; ++j)
      bfr[j] = *(const bf16x8*)(lds + 4096 + (wo * 64 + j * 16 + (lane & 15)) * 64 + kb);
#pragma unroll
    for (int i = 0; i < 2; ++i)
#pragma unroll
      for (int j = 0; j < 4; ++j)
        acc[i][j] = __builtin_amdgcn_mfma_f32_16x16x32_bf16(af[i], bfr[j], acc[i][j], 0, 0, 0);
    __syncthreads();
  }
#pragma unroll
  for (int i = 0; i < 2; ++i) {
#pragma unroll
    for (int j = 0; j < 4; ++j) {
      const int colg = (int)bo * 128 + wo * 64 + j * 16 + (lane & 15);
      const float bvv = bias[colg];
#pragma unroll
      for (int r = 0; r < 4; ++r) {
        const long rowg = bm * 64 + wm * 32 + i * 16 + (lane >> 4) * 4 + r;
        const float v = acc[i][j][r] + bvv;
        outb[rowg * 512 + colg] = f2bf(v > 0.f ? v : 0.f);
      }
    }
  }
}

// ---------- GEMM + bias + residual + LayerNorm fused epilogue ----------
// BM=16, BN=256 (full row per block), grid (M/16). KT = K/32.
template <int KT, int OUT_BF16, int RES_BF16>
__global__ __launch_bounds__(256, 2) void gemm_ln(
    const unsigned short* __restrict__ A,   // M x K bf16
    const unsigned short* __restrict__ W,   // 256 x K bf16
    const float* __restrict__ bias,         // 256
    const float* __restrict__ resf,         // M x 256 f32 (RES_BF16=0)
    const unsigned short* __restrict__ resb,// M x 256 bf16 (RES_BF16=1)
    const float* __restrict__ g, const float* __restrict__ b,
    float* __restrict__ outf,
    unsigned short* __restrict__ outb) {
  __shared__ __attribute__((aligned(16))) char lds[1024 + 16384];  // A 1KB | B 16KB
  __shared__ float2 part[4][16];
  const int tid = threadIdx.x, lane = tid & 63;
  const int wo = tid >> 6;
  const long bm = blockIdx.x;
  constexpr int K = KT * 32;

  f32x4 acc[4] = {};
  const char* Ab = (const char*)(A + bm * 16 * (long)K);
  for (int kt = 0; kt < KT; ++kt) {
    if (tid < 64) {
      const int fb = tid * 16;
      gload_lds16(Ab + (long)(fb >> 6) * (K * 2) + kt * 64 + (fb & 63), lds + fb);
    }
#pragma unroll
    for (int c = 0; c < 4; ++c) {
      const int fb = c * 4096 + tid * 16;
      gload_lds16((const char*)W + (long)(fb >> 6) * (K * 2) + kt * 64 + (fb & 63), lds + 1024 + fb);
    }
    __syncthreads();
    bf16x8 af, bfr[4];
    const int kb = (lane >> 4) * 16;
    af = *(const bf16x8*)(lds + ((lane & 15)) * 64 + kb);
#pragma unroll
    for (int j = 0; j < 4; ++j)
      bfr[j] = *(const bf16x8*)(lds + 1024 + (wo * 64 + j * 16 + (lane & 15)) * 64 + kb);
#pragma unroll
    for (int j = 0; j < 4; ++j)
      acc[j] = __builtin_amdgcn_mfma_f32_16x16x32_bf16(af, bfr[j], acc[j], 0, 0, 0);
    __syncthreads();
  }

  float gj[4], bj[4], biasj[4];
  int colg[4];
#pragma unroll
  for (int j = 0; j < 4; ++j) {
    colg[j] = wo * 64 + j * 16 + (lane & 15);
    gj[j] = g[colg[j]]; bj[j] = b[colg[j]]; biasj[j] = bias[colg[j]];
  }
  float v[4][4];
#pragma unroll
  for (int r = 0; r < 4; ++r) {
    const int row_local = (lane >> 4) * 4 + r;
    const long rowg = bm * 16 + row_local;
    float s = 0.f, s2 = 0.f;
#pragma unroll
    for (int j = 0; j < 4; ++j) {
      const float rv = RES_BF16 ? bf2f(resb[rowg * 256 + colg[j]]) : resf[rowg * 256 + colg[j]];
      float vv = acc[j][r] + biasj[j] + rv;
      v[j][r] = vv;
      s += vv; s2 = fmaf(vv, vv, s2);
    }
#pragma unroll
    for (int m = 8; m > 0; m >>= 1) { s += __shfl_xor(s, m, 16); s2 += __shfl_xor(s2, m, 16); }
    if ((lane & 15) == 0) part[wo][row_local] = make_float2(s, s2);
  }
  __syncthreads();
#pragma unroll
  for (int r = 0; r < 4; ++r) {
    const int row_local = (lane >> 4) * 4 + r;
    const long rowg = bm * 16 + row_local;
    float s = 0.f, s2 = 0.f;
#pragma unroll
    for (int wq = 0; wq < 4; ++wq) { s += part[wq][row_local].x; s2 += part[wq][row_local].y; }
    const float mu = s * (1.f / 256.f);
    const float var = s2 * (1.f / 256.f) - mu * mu;
    const float inv = rsqrtf(var + 1e-5f);
#pragma unroll
    for (int j = 0; j < 4; ++j) {
      const float y = (v[j][r] - mu) * inv * gj[j] + bj[j];
      if (OUT_BF16) outb[rowg * 256 + colg[j]] = f2bf(y);
      else outf[rowg * 256 + colg[j]] = y;
    }
  }
}

// ---------- fused gather + RPE rotary + MHA, head-half split for XCD-local L2 ----------
// grid 16384, 128 threads. bid -> xcd=bid&7; half=xcd>>2; n=(bid>>3)*4+(xcd&3).
// XCDs 0-3 touch only half 0 of kvp (4MB), XCDs 4-7 only half 1 -> per-XCD-L2-resident gather.
__global__ __launch_bounds__(128, 8) void attn3(
    const unsigned short* __restrict__ qb,   // N x 256 (bf16)
    const unsigned short* __restrict__ kvp,  // M x 512: [K0|V0|K1|V1] (bf16)
    const int* __restrict__ idx,             // N x 32
    const float* __restrict__ icoord,        // N x 3
    const float* __restrict__ mcoord,        // M x 3
    const float* __restrict__ mask,          // N x 32
    const float4* __restrict__ rpe4,         // 128 x {w0,w1,w2,b}
    unsigned short* __restrict__ hb)         // N x 256 (bf16)
{
  __shared__ int idx_s[32];
  __shared__ float4 relm_s[32];
  __shared__ float4 rpe_s[64];
  __shared__ __attribute__((aligned(16))) float p_s[128];
  __shared__ __attribute__((aligned(16))) unsigned short vls[32][128];

  const int bid = blockIdx.x, t = threadIdx.x;
  const int xcd = bid & 7;
  const int half = xcd >> 2;
  const int n = (bid >> 3) * 4 + (xcd & 3);

  if (t < 64) rpe_s[t] = rpe4[half * 64 + t];
  if (t < 32) {
    const int m = idx[n * 32 + t];
    idx_s[t] = m;
    float4 rm;
    rm.x = mcoord[(long)m * 3 + 0] - icoord[(long)n * 3 + 0];
    rm.y = mcoord[(long)m * 3 + 1] - icoord[(long)n * 3 + 1];
    rm.z = mcoord[(long)m * 3 + 2] - icoord[(long)n * 3 + 2];
    rm.w = mask[n * 32 + t];
    relm_s[t] = rm;
  }
  __syncthreads();

  // stage V-half (8KB): vls[k][0:128] = V[idx_s[k]][half*128 : half*128+128]
#pragma unroll
  for (int i = 0; i < 4; ++i) {
    const int b = i * 2048 + t * 16;
    const int r = b >> 8, cb = b & 255;
    gload_lds16((const char*)kvp + (long)idx_s[r] * 1024 + half * 512 + 256 + cb, (char*)vls + b);
  }

  const int h = t >> 5, k = t & 31;   // h: local head 0..3
  const float4 rm = relm_s[k];
  const long krow = idx_s[k];

  u16x8 kv8[4], qv8[4];
  {
    const u16x8* kp = (const u16x8*)((const char*)kvp + krow * 1024 + half * 512 + h * 64);
    const u16x8* qp = (const u16x8*)((const char*)qb + (long)n * 512 + half * 256 + h * 64);
#pragma unroll
    for (int i = 0; i < 4; ++i) { kv8[i] = kp[i]; qv8[i] = qp[i]; }
  }

  float sc = 0.f;
#pragma unroll
  for (int j2 = 0; j2 < 16; ++j2) {
    const float4 wj = rpe_s[h * 16 + j2];
    const float ang = fmaf(wj.x, rm.x, fmaf(wj.y, rm.y, fmaf(wj.z, rm.z, wj.w)));
    float sn, cs;
    __sincosf(ang, &sn, &cs);
    const int wi = j2 >> 2, e0 = (j2 & 3) * 2;
    const float x0 = bf2f(kv8[wi][e0]), x1 = bf2f(kv8[wi][e0 + 1]);
    const float q0 = bf2f(qv8[wi][e0]), q1 = bf2f(qv8[wi][e0 + 1]);
    const float k0 = fmaf(x0, cs, -x1 * sn);
    const float k1 = fmaf(x0, sn, x1 * cs);
    sc = fmaf(q0, k0, sc);
    sc = fmaf(q1, k1, sc);
  }
  sc = sc * 0.17677669529663687f - 1e6f * (1.f - rm.w);

  float mx = sc;
#pragma unroll
  for (int m = 16; m > 0; m >>= 1) mx = fmaxf(mx, __shfl_xor(mx, m, 32));
  const float e = __expf(sc - mx);
  float sum = e;
#pragma unroll
  for (int m = 16; m > 0; m >>= 1) sum += __shfl_xor(sum, m, 32);
  p_s[t] = e / sum;  // p_s[h*32 + k]
  __syncthreads();

  // PV: thread t = local output channel
  float acc = 0.f;
  const int h2 = t >> 5;
#pragma unroll
  for (int k4 = 0; k4 < 8; ++k4) {
    const float4 p4 = *(const float4*)(p_s + h2 * 32 + k4 * 4);
    acc = fmaf(p4.x, bf2f(vls[k4 * 4 + 0][t]), acc);
    acc = fmaf(p4.y, bf2f(vls[k4 * 4 + 1][t]), acc);
    acc = fmaf(p4.z, bf2f(vls[k4 * 4 + 2][t]), acc);
    acc = fmaf(p4.w, bf2f(vls[k4 * 4 + 3][t]), acc);
  }
  hb[(long)n * 256 + half * 128 + t] = f2bf(acc);
}

// ---------- launch ----------
extern "C" void kernel_launch(void* const* d_in, const int* in_sizes, int n_in,
                              void* d_out, int out_size, void* d_ws, size_t ws_size,
                              hipStream_t stream) {
  const float* x    = (const float*)d_in[0];
  const float* mem  = (const float*)d_in[1];
  const int* idx    = (const int*)d_in[2];
  const float* ic   = (const float*)d_in[3];
  const float* mc   = (const float*)d_in[4];
  const float* mask = (const float*)d_in[5];
  const float* Wq = (const float*)d_in[6];  const float* bq = (const float*)d_in[7];
  const float* Wk = (const float*)d_in[8];  const float* bk = (const float*)d_in[9];
  const float* Wv = (const float*)d_in[10]; const float* bv = (const float*)d_in[11];
  const float* Wo = (const float*)d_in[12]; const float* bo = (const float*)d_in[13];
  const float* g1 = (const float*)d_in[14]; const float* b1 = (const float*)d_in[15];
  const float* Wrpe = (const float*)d_in[16]; const float* brpe = (const float*)d_in[17];
  const float* We = (const float*)d_in[18]; const float* be = (const float*)d_in[19];
  const float* Ws = (const float*)d_in[20]; const float* bs = (const float*)d_in[21];
  const float* g2 = (const float*)d_in[22]; const float* b2 = (const float*)d_in[23];

  char* w = (char*)d_ws;
  const size_t MB = 1ull << 20;
  unsigned short* kvp   = (unsigned short*)(w + 0);        // 8MB (M x 512)
  unsigned short* qbuf  = (unsigned short*)(w + 8 * MB);   // 4MB
  unsigned short* hb    = (unsigned short*)(w + 12 * MB);  // 4MB
  unsigned short* out1b = (unsigned short*)(w + 16 * MB);  // 4MB
  unsigned short* ffb   = (unsigned short*)(w + 20 * MB);  // 8MB (8192x512)
  unsigned short* wqb  = (unsigned short*)(w + 28 * MB);   // 128KB
  unsigned short* wkvb = wqb + 65536;                      // 256KB (Wk|Wv)
  unsigned short* wob  = wkvb + 131072;                    // 128KB
  unsigned short* web  = wob + 65536;                      // 256KB
  unsigned short* wsb  = web + 131072;                     // 256KB
  float4*         rpe4 = (float4*)(wsb + 131072);          // 2KB

  // weights -> bf16 (+ rpe pack)
  wcvt<<<513, 256, 0, stream>>>(Wq, Wk, Wv, Wo, We, Ws, Wrpe, brpe,
                                wqb, wkvb, wob, web, wsb, rpe4);

  // fused q/k/v projections (f32 A reg-staged, bf16 W async)
  gemm_proj<<<dim3(128, 6), 256, 0, stream>>>(x, mem, wqb, wkvb, bq, bk, bv, qbuf, kvp);

  // fused gather + rotary + attention (head-half split, XCD-local)
  attn3<<<16384, 128, 0, stream>>>(qbuf, kvp, idx, ic, mc, mask, rpe4, hb);

  // output proj + residual(x, f32) + LN1 -> bf16
  gemm_ln<8, 1, 0><<<512, 256, 0, stream>>>(
      hb, wob, bo, x, nullptr, g1, b1, nullptr, out1b);

  // FFN1 (relu)
  gemm_relu<<<dim3(128, 4), 256, 0, stream>>>(out1b, web, be, ffb);

  // FFN2 + residual(out1b, bf16) + LN2 -> d_out (f32)
  gemm_ln<16, 0, 1><<<512, 256, 0, stream>>>(
      ffb, wsb, bs, nullptr, out1b, g2, b2, (float*)d_out, nullptr);
}